// Round 1
// baseline (4047.787 us; speedup 1.0000x reference)
//
#include <hip/hip_runtime.h>

namespace {

constexpr int B = 32, H = 512, L = 2, T = 20, V = 10000, S = 49;

__device__ __forceinline__ float sigf(float x) { return 1.0f / (1.0f + expf(-x)); }
__device__ __forceinline__ float dot4(float4 a, float4 b) {
  return a.x*b.x + a.y*b.y + a.z*b.z + a.w*b.w;
}

// ---------------- keys/values precompute (once) ----------------
// keys[b,d,s] = tanh(sum_j chan[b,d,j]*Wk[s,j] + bk[s]); same for values.
__global__ void kv_kernel(const float* __restrict__ chan,
                          const float* __restrict__ Wk, const float* __restrict__ bk,
                          const float* __restrict__ Wv, const float* __restrict__ bv,
                          float* __restrict__ keys, float* __restrict__ values) {
  int idx = blockIdx.x * 256 + threadIdx.x;   // exactly B*512*S = 802816
  int s = idx % S;
  int bd = idx / S;
  const float* cr = chan + bd * S;
  float ak = bk[s], av = bv[s];
  for (int j = 0; j < S; ++j) {
    float cv = cr[j];
    ak += cv * Wk[s * S + j];
    av += cv * Wv[s * S + j];
  }
  keys[idx] = tanhf(ak);
  values[idx] = tanhf(av);
}

// ---------------- state init (every call; ws is re-poisoned) ----------------
__global__ void init_kernel(const float* __restrict__ pooled,
                            const float* __restrict__ embed,
                            const int* __restrict__ sos,
                            float* __restrict__ emb, float* __restrict__ h,
                            float* __restrict__ c) {
  int idx = blockIdx.x * 256 + threadIdx.x;   // L*B*H = 32768
  float p = pooled[idx & (B * H - 1)];
  h[idx] = p;
  c[idx] = p;
  if (idx < B * H) emb[idx] = embed[sos[0] * H + (idx & (H - 1))];
}

// ---------------- fused LSTM cell (gates GEMM + elementwise) ----------------
// grid 256: blockIdx = bg(8 groups of 4 b) + hg(32 groups of 16 hi)*8
// thread: p = tid&3 (K-quarter), hi_local = (tid>>2)&15, b_local = tid>>6
__global__ __launch_bounds__(256) void lstm_kernel(
    const float* __restrict__ x, const float* __restrict__ h,
    const float* __restrict__ c,
    const float* __restrict__ Wih, const float* __restrict__ Whh,
    const float* __restrict__ bih, const float* __restrict__ bhh,
    float* __restrict__ hmid, float* __restrict__ cout) {
  __shared__ __align__(16) float xh[4][1032];   // [b_local][x(512)|h(512)], padded
  int tid = threadIdx.x;
  int bg = blockIdx.x & 7, hg = blockIdx.x >> 3;
  for (int i = tid; i < 4 * 1024; i += 256) {
    int row = i >> 10, col = i & 1023;
    int b = bg * 4 + row;
    xh[row][col] = (col < 512) ? x[b * H + col] : h[b * H + (col - 512)];
  }
  __syncthreads();

  int p = tid & 3, hl = (tid >> 2) & 15, bl = tid >> 6;
  int hi = hg * 16 + hl;
  const float* W = (p < 2) ? Wih : Whh;
  int kw0 = (p & 1) * 256;   // K-offset within the chosen matrix
  int kx0 = p * 256;         // offset into concatenated [x|h]
  const float* xr = &xh[bl][kx0];
  const float* w0 = W + (0 * H + hi) * H + kw0;
  const float* w1 = W + (1 * H + hi) * H + kw0;
  const float* w2 = W + (2 * H + hi) * H + kw0;
  const float* w3 = W + (3 * H + hi) * H + kw0;
  float a0 = 0.f, a1 = 0.f, a2 = 0.f, a3 = 0.f;
  for (int k = 0; k < 256; k += 4) {
    float4 xv = *(const float4*)&xr[k];
    a0 += dot4(xv, *(const float4*)&w0[k]);
    a1 += dot4(xv, *(const float4*)&w1[k]);
    a2 += dot4(xv, *(const float4*)&w2[k]);
    a3 += dot4(xv, *(const float4*)&w3[k]);
  }
  // sum the 4 K-quarter partials (p lives in lane bits 0..1)
  a0 += __shfl_xor(a0, 1); a0 += __shfl_xor(a0, 2);
  a1 += __shfl_xor(a1, 1); a1 += __shfl_xor(a1, 2);
  a2 += __shfl_xor(a2, 1); a2 += __shfl_xor(a2, 2);
  a3 += __shfl_xor(a3, 1); a3 += __shfl_xor(a3, 2);
  if (p == 0) {
    int b = bg * 4 + bl;
    float gi = a0 + bih[0 * H + hi] + bhh[0 * H + hi];
    float gf = a1 + bih[1 * H + hi] + bhh[1 * H + hi];
    float gg = a2 + bih[2 * H + hi] + bhh[2 * H + hi];
    float go = a3 + bih[3 * H + hi] + bhh[3 * H + hi];
    float cold = c[b * H + hi];
    float c2 = sigf(gf) * cold + sigf(gi) * tanhf(gg);
    hmid[b * H + hi] = sigf(go) * tanhf(c2);
    cout[b * H + hi] = c2;
  }
}

// ---------------- vocab projection (logits + output column) ----------------
// grid 314: blockIdx = bg(2 groups of 16 b) + vg(157 groups of 64 v)*2
__global__ __launch_bounds__(256) void proj_kernel(
    const float* __restrict__ x, const float* __restrict__ projW,
    const float* __restrict__ projb, float* __restrict__ logits,
    float* __restrict__ out, int tcol) {
  __shared__ __align__(16) float xs[16][516];
  int tid = threadIdx.x;
  int bg = blockIdx.x & 1, vg = blockIdx.x >> 1;
  for (int i = tid; i < 16 * 512; i += 256) {
    int r = i >> 9, col = i & 511;
    xs[r][col] = x[(bg * 16 + r) * H + col];
  }
  __syncthreads();
  int bl = tid & 15, vl = tid >> 4;   // vl: 0..15
  int b = bg * 16 + bl;
  int v0 = vg * 64 + vl * 4;
  const float* wr[4];
  float acc[4];
#pragma unroll
  for (int j = 0; j < 4; ++j) {
    int v = v0 + j; if (v > V - 1) v = V - 1;
    wr[j] = projW + (size_t)v * H;
    acc[j] = projb[v];
  }
  const float* xr = xs[bl];
  for (int k = 0; k < 512; k += 4) {
    float4 xv = *(const float4*)&xr[k];
#pragma unroll
    for (int j = 0; j < 4; ++j)
      acc[j] += dot4(xv, *(const float4*)&wr[j][k]);
  }
#pragma unroll
  for (int j = 0; j < 4; ++j) {
    int v = v0 + j;
    if (v < V) {
      logits[b * V + v] = acc[j];
      out[((size_t)b * V + v) * T + tcol] = acc[j];
    }
  }
}

// ---------------- greedy argmax + embedding gather ----------------
__global__ __launch_bounds__(256) void argmax_embed_kernel(
    const float* __restrict__ logits, const float* __restrict__ embed,
    float* __restrict__ emb) {
  __shared__ float sv[256];
  __shared__ int si[256];
  int b = blockIdx.x, tid = threadIdx.x;
  float best = -3.4e38f;
  int bi = 0x7fffffff;
  for (int v = tid; v < V; v += 256) {
    float val = logits[b * V + v];
    if (val > best) { best = val; bi = v; }   // strided v is increasing -> first-max kept
  }
  sv[tid] = best; si[tid] = bi;
  __syncthreads();
  for (int st = 128; st > 0; st >>= 1) {
    if (tid < st) {
      float ov = sv[tid + st]; int oi = si[tid + st];
      if (ov > sv[tid] || (ov == sv[tid] && oi < si[tid])) { sv[tid] = ov; si[tid] = oi; }
    }
    __syncthreads();
  }
  int idx = si[0];
  for (int i = tid; i < H; i += 256) emb[b * H + i] = embed[(size_t)idx * H + i];
}

// ---------------- q -> scores -> softmax -> attn -> cat (per (l,b)) --------
__global__ __launch_bounds__(256) void qk_attn_kernel(
    const float* __restrict__ hmid, const float* __restrict__ Wq,
    const float* __restrict__ bq, const float* __restrict__ keys,
    const float* __restrict__ values, float* __restrict__ cat) {
  __shared__ __align__(16) float hvec[512];
  __shared__ __align__(16) float qvec[512];
  __shared__ float wts[64];
  int lb = blockIdx.x, tid = threadIdx.x;
  int b = lb & 31;
  const float* hrow = hmid + lb * H;
  hvec[tid] = hrow[tid];
  hvec[tid + 256] = hrow[tid + 256];
  __syncthreads();
  // q row (full 512x512 GEMV per block)
  for (int jj = 0; jj < 2; ++jj) {
    int j = tid + jj * 256;
    float acc = bq[j];
    const float* wr = Wq + j * H;
    for (int k = 0; k < 512; k += 4)
      acc += dot4(*(const float4*)&hvec[k], *(const float4*)&wr[k]);
    qvec[j] = tanhf(acc);
  }
  __syncthreads();
  // scores + softmax in wave 0
  if (tid < 64) {
    float sc = -3.4e38f;
    if (tid < S) {
      const float* kb = keys + (size_t)b * 512 * S;
      float acc = 0.f;
      for (int d = 0; d < 512; d += 4) {
        acc += qvec[d]     * kb[(d    ) * S + tid];
        acc += qvec[d + 1] * kb[(d + 1) * S + tid];
        acc += qvec[d + 2] * kb[(d + 2) * S + tid];
        acc += qvec[d + 3] * kb[(d + 3) * S + tid];
      }
      sc = acc * (1.0f / 7.0f);
    }
    float m = sc;
    for (int o = 32; o > 0; o >>= 1) m = fmaxf(m, __shfl_xor(m, o));
    float e = (tid < S) ? expf(sc - m) : 0.f;
    float sum = e;
    for (int o = 32; o > 0; o >>= 1) sum += __shfl_xor(sum, o);
    if (tid < S) wts[tid] = e / sum;
  }
  __syncthreads();
  // attn + concat [attn | hmid]
  const float* vb = values + (size_t)b * 512 * S;
  for (int jj = 0; jj < 2; ++jj) {
    int d = tid + jj * 256;
    const float* vr = vb + d * S;
    float acc = 0.f;
    for (int s = 0; s < S; ++s) acc += wts[s] * vr[s];
    cat[lb * 1024 + d] = acc;
    cat[lb * 1024 + 512 + d] = hvec[d];
  }
}

// ---------------- gated hidden update: h = tanh(cat @ hattW^T + hattb) -----
// grid 64: blockIdx = lbg(8 groups of 8 lb) + jg(8 groups of 64 j)*8
__global__ __launch_bounds__(256) void hatt_kernel(
    const float* __restrict__ cat, const float* __restrict__ hattW,
    const float* __restrict__ hattb, float* __restrict__ h) {
  __shared__ __align__(16) float cl[8][1028];
  int tid = threadIdx.x;
  int lbg = blockIdx.x & 7, jg = blockIdx.x >> 3;
  for (int i = tid; i < 8 * 1024; i += 256) {
    int r = i >> 10, col = i & 1023;
    cl[r][col] = cat[(lbg * 8 + r) * 1024 + col];
  }
  __syncthreads();
  int lbl = tid & 7, jl = tid >> 3;   // jl 0..31
  int lb = lbg * 8 + lbl;
  int j0 = jg * 64 + jl, j1 = j0 + 32;
  float acc0 = hattb[j0], acc1 = hattb[j1];
  const float* w0 = hattW + j0 * 1024;
  const float* w1 = hattW + j1 * 1024;
  const float* cr = cl[lbl];
  for (int k = 0; k < 1024; k += 4) {
    float4 c4 = *(const float4*)&cr[k];
    acc0 += dot4(c4, *(const float4*)&w0[k]);
    acc1 += dot4(c4, *(const float4*)&w1[k]);
  }
  h[lb * H + j0] = tanhf(acc0);
  h[lb * H + j1] = tanhf(acc1);
}

}  // namespace

extern "C" void kernel_launch(void* const* d_in, const int* in_sizes, int n_in,
                              void* d_out, int out_size, void* d_ws, size_t ws_size,
                              hipStream_t stream) {
  const float* chan   = (const float*)d_in[0];
  const float* pooled = (const float*)d_in[1];
  const float* embed  = (const float*)d_in[2];
  const float* Wq     = (const float*)d_in[3];
  const float* bq     = (const float*)d_in[4];
  const float* Wk     = (const float*)d_in[5];
  const float* bk     = (const float*)d_in[6];
  const float* Wv     = (const float*)d_in[7];
  const float* bv     = (const float*)d_in[8];
  const float* Wih    = (const float*)d_in[9];
  const float* Whh    = (const float*)d_in[10];
  const float* bih    = (const float*)d_in[11];
  const float* bhh    = (const float*)d_in[12];
  const float* projW  = (const float*)d_in[13];
  const float* projb  = (const float*)d_in[14];
  const float* hattW  = (const float*)d_in[15];
  const float* hattb  = (const float*)d_in[16];
  const int*   sos    = (const int*)d_in[17];

  float* out = (float*)d_out;
  float* ws  = (float*)d_ws;

  float* keys   = ws;                       // B*512*S
  float* values = keys + B * 512 * S;       // B*512*S
  float* emb    = values + B * 512 * S;     // B*H
  float* h      = emb + B * H;              // L*B*H
  float* c      = h + L * B * H;            // L*B*H
  float* hmid   = c + L * B * H;            // L*B*H
  float* cat    = hmid + L * B * H;         // L*B*1024
  float* logits = cat + L * B * 1024;       // B*V

  kv_kernel<<<(B * 512 * S) / 256, 256, 0, stream>>>(chan, Wk, bk, Wv, bv, keys, values);
  init_kernel<<<(L * B * H) / 256, 256, 0, stream>>>(pooled, embed, sos, emb, h, c);
  proj_kernel<<<314, 256, 0, stream>>>(emb, projW, projb, logits, out, 0);

  for (int t = 0; t < T - 1; ++t) {
    lstm_kernel<<<256, 256, 0, stream>>>(emb, h, c, Wih, Whh, bih, bhh, hmid, c);
    lstm_kernel<<<256, 256, 0, stream>>>(hmid, h + B * H, c + B * H,
                                         Wih + 4 * H * H, Whh + 4 * H * H,
                                         bih + 4 * H, bhh + 4 * H,
                                         hmid + B * H, c + B * H);
    proj_kernel<<<314, 256, 0, stream>>>(hmid + B * H, projW, projb, logits, out, t + 1);
    qk_attn_kernel<<<L * B, 256, 0, stream>>>(hmid, Wq, bq, keys, values, cat);
    argmax_embed_kernel<<<B, 256, 0, stream>>>(logits, embed, emb);
    hatt_kernel<<<64, 256, 0, stream>>>(cat, hattW, hattb, h);
  }
}

// Round 2
// 3340.963 us; speedup vs baseline: 1.2116x; 1.2116x over previous
//
#include <hip/hip_runtime.h>

namespace {

constexpr int B = 32, H = 512, L = 2, T = 20, V = 10000, S = 49;

__device__ __forceinline__ float sigf(float x) { return 1.0f / (1.0f + expf(-x)); }
__device__ __forceinline__ float dot4(float4 a, float4 b) {
  return a.x*b.x + a.y*b.y + a.z*b.z + a.w*b.w;
}

// ---------------- keys/values precompute (once), TRANSPOSED layout ---------
// keysT[b][s][d] = tanh(sum_j chan[b,d,j]*Wk[s,j] + bk[s]); valuesT same w/ Wv.
__global__ void kv_kernel(const float* __restrict__ chan,
                          const float* __restrict__ Wk, const float* __restrict__ bk,
                          const float* __restrict__ Wv, const float* __restrict__ bv,
                          float* __restrict__ keysT, float* __restrict__ valuesT) {
  int idx = blockIdx.x * 256 + threadIdx.x;   // (b*49+s)*512 + d, exact 802816
  int d = idx & 511;
  int bs = idx >> 9;
  int s = bs % 49;
  int b = bs / 49;
  const float* cr = chan + ((size_t)b * 512 + d) * S;
  float ak = bk[s], av = bv[s];
  for (int j = 0; j < S; ++j) {
    float cv = cr[j];
    ak += cv * Wk[s * S + j];
    av += cv * Wv[s * S + j];
  }
  keysT[idx] = tanhf(ak);
  valuesT[idx] = tanhf(av);
}

// ---------------- state init ----------------
__global__ void init_kernel(const float* __restrict__ pooled,
                            const float* __restrict__ embed,
                            const int* __restrict__ sos,
                            float* __restrict__ emb, float* __restrict__ h,
                            float* __restrict__ c) {
  int idx = blockIdx.x * 256 + threadIdx.x;   // L*B*H = 32768
  float p = pooled[idx & (B * H - 1)];
  h[idx] = p;
  c[idx] = p;
  if (idx < B * H) emb[idx] = embed[sos[0] * H + (idx & (H - 1))];
}

// ---------------- fused LSTM cell ----------------
// grid 512: bg(8 groups of 4 b) + hg(64 groups of 8 hi)*8
// thread: p = tid&7 (K-eighth; p<4 -> Wih, p>=4 -> Whh), hl=(tid>>3)&7, bl=tid>>6
__global__ __launch_bounds__(256) void lstm_kernel(
    const float* __restrict__ x, const float* __restrict__ h,
    const float* __restrict__ c,
    const float* __restrict__ Wih, const float* __restrict__ Whh,
    const float* __restrict__ bih, const float* __restrict__ bhh,
    float* __restrict__ hout, float* __restrict__ cout) {
  // 8 chunks of 132 (128 data + 4 skew) per row -> p-stride hits distinct banks
  __shared__ __align__(16) float xh[4][1056];
  int tid = threadIdx.x;
  int bg = blockIdx.x & 7, hg = blockIdx.x >> 3;
  for (int i = tid; i < 4 * 1024; i += 256) {
    int row = i >> 10, col = i & 1023;
    int b = bg * 4 + row;
    float v = (col < 512) ? x[b * H + col] : h[b * H + (col - 512)];
    xh[row][(col >> 7) * 132 + (col & 127)] = v;
  }
  __syncthreads();

  int p = tid & 7, hl = (tid >> 3) & 7, bl = tid >> 6;
  int hi = hg * 8 + hl;
  const float* W = (p < 4) ? Wih : Whh;
  int kw0 = (p & 3) * 128;
  const float* xr = &xh[bl][p * 132];
  const float* w0 = W + (size_t)(0 * H + hi) * H + kw0;
  const float* w1 = W + (size_t)(1 * H + hi) * H + kw0;
  const float* w2 = W + (size_t)(2 * H + hi) * H + kw0;
  const float* w3 = W + (size_t)(3 * H + hi) * H + kw0;
  float a0 = 0.f, a1 = 0.f, a2 = 0.f, a3 = 0.f;
  for (int k = 0; k < 128; k += 4) {
    float4 xv = *(const float4*)&xr[k];
    a0 += dot4(xv, *(const float4*)&w0[k]);
    a1 += dot4(xv, *(const float4*)&w1[k]);
    a2 += dot4(xv, *(const float4*)&w2[k]);
    a3 += dot4(xv, *(const float4*)&w3[k]);
  }
  a0 += __shfl_xor(a0, 1); a0 += __shfl_xor(a0, 2); a0 += __shfl_xor(a0, 4);
  a1 += __shfl_xor(a1, 1); a1 += __shfl_xor(a1, 2); a1 += __shfl_xor(a1, 4);
  a2 += __shfl_xor(a2, 1); a2 += __shfl_xor(a2, 2); a2 += __shfl_xor(a2, 4);
  a3 += __shfl_xor(a3, 1); a3 += __shfl_xor(a3, 2); a3 += __shfl_xor(a3, 4);
  if (p == 0) {
    int b = bg * 4 + bl;
    float gi = a0 + bih[0 * H + hi] + bhh[0 * H + hi];
    float gf = a1 + bih[1 * H + hi] + bhh[1 * H + hi];
    float gg = a2 + bih[2 * H + hi] + bhh[2 * H + hi];
    float go = a3 + bih[3 * H + hi] + bhh[3 * H + hi];
    float cold = c[b * H + hi];
    float c2 = sigf(gf) * cold + sigf(gi) * tanhf(gg);
    hout[b * H + hi] = sigf(go) * tanhf(c2);
    cout[b * H + hi] = c2;
  }
}

// ---------------- vocab projection ----------------
// grid 1252: bg(4 groups of 8 b) + vg(313 groups of 32 v)*4
// thread: kh=tid&1 (K-half), bl=(tid>>1)&7, vl=tid>>4 (16 slots x 2 v)
__global__ __launch_bounds__(256) void proj_kernel(
    const float* __restrict__ x, const float* __restrict__ projW,
    const float* __restrict__ projb, float* __restrict__ logits,
    float* __restrict__ outp, int tcol) {
  __shared__ __align__(16) float xs[8][516];
  int tid = threadIdx.x;
  int bg = blockIdx.x & 3, vg = blockIdx.x >> 2;
  for (int i = tid; i < 8 * 512; i += 256) {
    int r = i >> 9, col = i & 511;
    xs[r][col] = x[(bg * 8 + r) * H + col];
  }
  __syncthreads();
  int kh = tid & 1, bl = (tid >> 1) & 7, vl = tid >> 4;
  int b = bg * 8 + bl;
  int v0 = vg * 32 + vl * 2;
  int va = min(v0, V - 1), vb = min(v0 + 1, V - 1);
  const float* w0 = projW + (size_t)va * H + kh * 256;
  const float* w1 = projW + (size_t)vb * H + kh * 256;
  const float* xr = &xs[bl][kh * 256];
  float a0 = 0.f, a1 = 0.f;
  for (int k = 0; k < 256; k += 4) {
    float4 xv = *(const float4*)&xr[k];
    a0 += dot4(xv, *(const float4*)&w0[k]);
    a1 += dot4(xv, *(const float4*)&w1[k]);
  }
  a0 += __shfl_xor(a0, 1);
  a1 += __shfl_xor(a1, 1);
  if (kh == 0) {
    if (v0 < V) {
      float r = a0 + projb[v0];
      logits[b * V + v0] = r;
      if (outp) outp[((size_t)b * V + v0) * T + tcol] = r;
    }
    if (v0 + 1 < V) {
      float r = a1 + projb[v0 + 1];
      logits[b * V + v0 + 1] = r;
      if (outp) outp[((size_t)b * V + v0 + 1) * T + tcol] = r;
    }
  }
}

// ---------------- greedy argmax + embedding gather ----------------
__global__ __launch_bounds__(256) void argmax_embed_kernel(
    const float* __restrict__ logits, const float* __restrict__ embed,
    float* __restrict__ emb) {
  __shared__ float sv[256];
  __shared__ int si[256];
  int b = blockIdx.x, tid = threadIdx.x;
  float best = -3.4e38f;
  int bi = 0x7fffffff;
  for (int it = 0; it < 10; ++it) {
    int v0 = it * 1024 + tid * 4;
    if (v0 < V) {   // V%4==0 -> whole float4 valid
      float4 lv = *(const float4*)&logits[b * V + v0];
      if (lv.x > best) { best = lv.x; bi = v0; }
      if (lv.y > best) { best = lv.y; bi = v0 + 1; }
      if (lv.z > best) { best = lv.z; bi = v0 + 2; }
      if (lv.w > best) { best = lv.w; bi = v0 + 3; }
    }
  }
  sv[tid] = best; si[tid] = bi;
  __syncthreads();
  for (int st = 128; st > 0; st >>= 1) {
    if (tid < st) {
      float ov = sv[tid + st]; int oi = si[tid + st];
      if (ov > sv[tid] || (ov == sv[tid] && oi < si[tid])) { sv[tid] = ov; si[tid] = oi; }
    }
    __syncthreads();
  }
  int idx = si[0];
  for (int i = tid; i < H; i += 256) emb[b * H + i] = embed[(size_t)idx * H + i];
}

// ---------------- q GEMV: q[lb][j] = tanh(hmid[lb]@Wq.T + bq) ----------------
// grid 128: lbg(4 groups of 16 lb) + jg(32 groups of 16 j)*4
// thread: kh=tid&1, jl=(tid>>1)&15, lbl=tid>>5 (handles lbl and lbl+8)
__global__ __launch_bounds__(256) void q_kernel(
    const float* __restrict__ hmid, const float* __restrict__ Wq,
    const float* __restrict__ bq, float* __restrict__ q) {
  __shared__ __align__(16) float hm[16][516];
  int tid = threadIdx.x;
  int lbg = blockIdx.x & 3, jg = blockIdx.x >> 2;
  for (int i = tid; i < 16 * 512; i += 256) {
    int r = i >> 9, col = i & 511;
    hm[r][col] = hmid[(lbg * 16 + r) * H + col];
  }
  __syncthreads();
  int kh = tid & 1, jl = (tid >> 1) & 15, lbl = tid >> 5;
  int j = jg * 16 + jl;
  const float* wr = Wq + (size_t)j * H + kh * 256;
  const float* x0 = &hm[lbl][kh * 256];
  const float* x1 = &hm[lbl + 8][kh * 256];
  float a0 = 0.f, a1 = 0.f;
  for (int k = 0; k < 256; k += 4) {
    float4 wv = *(const float4*)&wr[k];
    a0 += dot4(*(const float4*)&x0[k], wv);
    a1 += dot4(*(const float4*)&x1[k], wv);
  }
  a0 += __shfl_xor(a0, 1);
  a1 += __shfl_xor(a1, 1);
  if (kh == 0) {
    q[(lbg * 16 + lbl) * H + j]     = tanhf(a0 + bq[j]);
    q[(lbg * 16 + lbl + 8) * H + j] = tanhf(a1 + bq[j]);
  }
}

// ---------------- scores -> softmax -> attn -> cat (per lb) ----------------
__global__ __launch_bounds__(256) void sattn_kernel(
    const float* __restrict__ q, const float* __restrict__ keysT,
    const float* __restrict__ valuesT, const float* __restrict__ hmid,
    float* __restrict__ cat) {
  __shared__ __align__(16) float qv[528];   // 4 chunks of 132 (128+4 skew)
  __shared__ float scl[64];
  __shared__ float wts[64];
  int lb = blockIdx.x, tid = threadIdx.x;
  int b = lb & 31;
  {
    int c0 = tid, c1 = tid + 256;
    qv[(c0 >> 7) * 132 + (c0 & 127)] = q[lb * H + c0];
    qv[(c1 >> 7) * 132 + (c1 & 127)] = q[lb * H + c1];
  }
  __syncthreads();
  // scores: thread (kq 0..3, sl 0..63)
  int kq = tid & 3, sl = tid >> 2;
  float acc = 0.f;
  if (sl < S) {
    const float* kr = keysT + ((size_t)b * S + sl) * H + kq * 128;
    const float* qr = &qv[kq * 132];
    for (int k = 0; k < 128; k += 4)
      acc += dot4(*(const float4*)&qr[k], *(const float4*)&kr[k]);
  }
  acc += __shfl_xor(acc, 1);
  acc += __shfl_xor(acc, 2);
  if (kq == 0 && sl < S) scl[sl] = acc * (1.0f / 7.0f);
  __syncthreads();
  if (tid < 64) {
    float sc = (tid < S) ? scl[tid] : -3.4e38f;
    float m = sc;
    for (int o = 32; o > 0; o >>= 1) m = fmaxf(m, __shfl_xor(m, o));
    float e = (tid < S) ? expf(sc - m) : 0.f;
    float sum = e;
    for (int o = 32; o > 0; o >>= 1) sum += __shfl_xor(sum, o);
    if (tid < S) wts[tid] = e / sum;
  }
  __syncthreads();
  // attn (coalesced over valuesT) + concat [attn | hmid]
  float acc0 = 0.f, acc1 = 0.f;
  for (int s = 0; s < S; ++s) {
    float w = wts[s];
    const float* vr = valuesT + ((size_t)b * S + s) * H;
    acc0 += w * vr[tid];
    acc1 += w * vr[tid + 256];
  }
  cat[lb * 1024 + tid] = acc0;
  cat[lb * 1024 + tid + 256] = acc1;
  cat[lb * 1024 + 512 + tid] = hmid[lb * H + tid];
  cat[lb * 1024 + 768 + tid] = hmid[lb * H + tid + 256];
}

// ---------------- gated hidden update: h = tanh(cat @ hattW^T + hattb) -----
// grid 128: lbg(8 groups of 8 lb) + jg(16 groups of 32 j)*8
// thread: kh=tid&1, lbl=(tid>>1)&3 (handles lbl and lbl+4), jl=tid>>3
__global__ __launch_bounds__(256) void hatt_kernel(
    const float* __restrict__ cat, const float* __restrict__ hattW,
    const float* __restrict__ hattb, float* __restrict__ h) {
  __shared__ __align__(16) float cl[8][1032];
  int tid = threadIdx.x;
  int lbg = blockIdx.x & 7, jg = blockIdx.x >> 3;
  for (int i = tid; i < 8 * 1024; i += 256) {
    int r = i >> 10, col = i & 1023;
    cl[r][col] = cat[(lbg * 8 + r) * 1024 + col];
  }
  __syncthreads();
  int kh = tid & 1, lbl = (tid >> 1) & 3, jl = tid >> 3;
  int j = jg * 32 + jl;
  const float* wr = hattW + (size_t)j * 1024 + kh * 512;
  const float* c0 = &cl[lbl][kh * 512];
  const float* c1 = &cl[lbl + 4][kh * 512];
  float a0 = 0.f, a1 = 0.f;
  for (int k = 0; k < 512; k += 4) {
    float4 wv = *(const float4*)&wr[k];
    a0 += dot4(*(const float4*)&c0[k], wv);
    a1 += dot4(*(const float4*)&c1[k], wv);
  }
  a0 += __shfl_xor(a0, 1);
  a1 += __shfl_xor(a1, 1);
  if (kh == 0) {
    h[(lbg * 8 + lbl) * H + j]     = tanhf(a0 + hattb[j]);
    h[(lbg * 8 + lbl + 4) * H + j] = tanhf(a1 + hattb[j]);
  }
}

// ---------------- final transpose (staged mode): slog[t][b][v] -> out[b][v][t]
__global__ __launch_bounds__(256) void finalize_kernel(
    const float* __restrict__ slog, float* __restrict__ outp) {
  int idx = blockIdx.x * 256 + threadIdx.x;   // b*V + v, exact 320000
  float vals[T];
#pragma unroll
  for (int t = 0; t < T; ++t) vals[t] = slog[(size_t)t * (B * V) + idx];
#pragma unroll
  for (int t = 0; t < T; t += 4)
    *(float4*)&outp[(size_t)idx * T + t] =
        make_float4(vals[t], vals[t + 1], vals[t + 2], vals[t + 3]);
}

}  // namespace

extern "C" void kernel_launch(void* const* d_in, const int* in_sizes, int n_in,
                              void* d_out, int out_size, void* d_ws, size_t ws_size,
                              hipStream_t stream) {
  const float* chan   = (const float*)d_in[0];
  const float* pooled = (const float*)d_in[1];
  const float* embed  = (const float*)d_in[2];
  const float* Wq     = (const float*)d_in[3];
  const float* bq     = (const float*)d_in[4];
  const float* Wk     = (const float*)d_in[5];
  const float* bk     = (const float*)d_in[6];
  const float* Wv     = (const float*)d_in[7];
  const float* bv     = (const float*)d_in[8];
  const float* Wih    = (const float*)d_in[9];
  const float* Whh    = (const float*)d_in[10];
  const float* bih    = (const float*)d_in[11];
  const float* bhh    = (const float*)d_in[12];
  const float* projW  = (const float*)d_in[13];
  const float* projb  = (const float*)d_in[14];
  const float* hattW  = (const float*)d_in[15];
  const float* hattb  = (const float*)d_in[16];
  const int*   sos    = (const int*)d_in[17];

  float* out = (float*)d_out;
  float* ws  = (float*)d_ws;

  float* keysT   = ws;                        // B*S*512
  float* valuesT = keysT + B * S * 512;       // B*S*512
  float* emb     = valuesT + B * S * 512;     // B*H
  float* h       = emb + B * H;               // L*B*H
  float* c       = h + L * B * H;             // L*B*H
  float* hmid    = c + L * B * H;             // L*B*H
  float* cat     = hmid + L * B * H;          // L*B*1024
  float* q       = cat + L * B * 1024;        // L*B*H
  float* slog    = q + L * B * H;             // T*B*V (staged) or B*V (direct)

  size_t base_floats = (size_t)(slog - ws);
  bool staged = ws_size >= (base_floats + (size_t)T * B * V) * sizeof(float);
  float* direct_out = staged ? nullptr : out;

  kv_kernel<<<(B * S * 512) / 256, 256, 0, stream>>>(chan, Wk, bk, Wv, bv, keysT, valuesT);
  init_kernel<<<(L * B * H) / 256, 256, 0, stream>>>(pooled, embed, sos, emb, h, c);
  {
    float* lg = staged ? slog : slog;  // column 0
    proj_kernel<<<1252, 256, 0, stream>>>(emb, projW, projb, lg, direct_out, 0);
  }

  for (int t = 0; t < T - 1; ++t) {
    float* lg = staged ? (slog + (size_t)(t + 1) * B * V) : slog;
    lstm_kernel<<<512, 256, 0, stream>>>(emb, h, c, Wih, Whh, bih, bhh, hmid, c);
    lstm_kernel<<<512, 256, 0, stream>>>(hmid, h + B * H, c + B * H,
                                         Wih + 4 * H * H, Whh + 4 * H * H,
                                         bih + 4 * H, bhh + 4 * H,
                                         hmid + B * H, c + B * H);
    proj_kernel<<<1252, 256, 0, stream>>>(hmid + B * H, projW, projb, lg, direct_out, t + 1);
    q_kernel<<<128, 256, 0, stream>>>(hmid, Wq, bq, q);
    sattn_kernel<<<L * B, 256, 0, stream>>>(q, keysT, valuesT, hmid, cat);
    hatt_kernel<<<128, 256, 0, stream>>>(cat, hattW, hattb, h);
    argmax_embed_kernel<<<B, 256, 0, stream>>>(lg, embed, emb);
  }

  if (staged) finalize_kernel<<<(B * V) / 256, 256, 0, stream>>>(slog, out);
}

// Round 3
// 1982.851 us; speedup vs baseline: 2.0414x; 1.6849x over previous
//
#include <hip/hip_runtime.h>

namespace {

constexpr int B = 32, H = 512, L = 2, T = 20, V = 10000, S = 49;

__device__ __forceinline__ float sigf(float x) { return 1.0f / (1.0f + expf(-x)); }
__device__ __forceinline__ float dot4(float4 a, float4 b) {
  return a.x*b.x + a.y*b.y + a.z*b.z + a.w*b.w;
}

// ---------------- keys/values precompute (once) ----------------
// grid 256 = b(32) x dtile(8 of 64 d). chan staged once per block.
__global__ __launch_bounds__(256) void kv_kernel(
    const float* __restrict__ chan,
    const float* __restrict__ Wk, const float* __restrict__ bk,
    const float* __restrict__ Wv, const float* __restrict__ bv,
    float* __restrict__ keysT, float* __restrict__ valuesT) {
  __shared__ float ch[64][52];
  __shared__ float wk[49][52], wv[49][52];
  int b = blockIdx.x >> 3, dt = blockIdx.x & 7;
  int tid = threadIdx.x;
  for (int i = tid; i < 49 * 49; i += 256) {
    int s = i / 49, j = i % 49;
    wk[s][j] = Wk[i]; wv[s][j] = Wv[i];
  }
  for (int i = tid; i < 64 * 49; i += 256) {
    int d = i / 49, j = i % 49;
    ch[d][j] = chan[((size_t)b * 512 + dt * 64 + d) * S + j];
  }
  __syncthreads();
  int dl = tid >> 2, sq = tid & 3;
  for (int s = sq; s < S; s += 4) {
    float ak = bk[s], av = bv[s];
    for (int j = 0; j < 49; ++j) {
      float cv = ch[dl][j];
      ak += cv * wk[s][j];
      av += cv * wv[s][j];
    }
    int d = dt * 64 + dl;
    keysT[((size_t)b * S + s) * H + d] = tanhf(ak);
    valuesT[((size_t)b * S + s) * H + d] = tanhf(av);
  }
}

// ---------------- state init ----------------
__global__ void init_kernel(const float* __restrict__ pooled,
                            const float* __restrict__ embed,
                            const int* __restrict__ sos,
                            float* __restrict__ emb, float* __restrict__ h,
                            float* __restrict__ c) {
  int idx = blockIdx.x * 256 + threadIdx.x;   // L*B*H = 32768
  float p = pooled[idx & (B * H - 1)];
  h[idx] = p;
  c[idx] = p;
  if (idx < B * H) emb[idx] = embed[sos[0] * H + (idx & (H - 1))];
}

// ---------------- LSTM cell: one block per hi, all gates+batches ----------
// grid 512 (hi). thread = ko(16, K-sixteenth) x rr(4, gate) x bh(4, 8 batches)
// Weights fetched exactly once per dispatch (~8 MB total).
__global__ __launch_bounds__(256) void lstm_kernel(
    const float* __restrict__ x, const float* __restrict__ hprev,
    const float* __restrict__ cprev,
    const float* __restrict__ Wih, const float* __restrict__ Whh,
    const float* __restrict__ bih, const float* __restrict__ bhh,
    float* __restrict__ hout, float* __restrict__ cout) {
  __shared__ __align__(16) float smem[32 * 512];   // 64 KB
  int tid = threadIdx.x;
  int hi = blockIdx.x;
  int ko = tid & 15, rr = (tid >> 4) & 3, bh = tid >> 6;

  {  // stage x
    const float4* xg = (const float4*)x;
    float4* s4 = (float4*)smem;
    for (int i = tid; i < 4096; i += 256) s4[i] = xg[i];
  }
  __syncthreads();

  float acc[8];
#pragma unroll
  for (int j = 0; j < 8; ++j) acc[j] = 0.f;
  {  // phase 1: x @ Wih[row]^T
    const float* wrow = Wih + ((size_t)rr * H + hi) * H;
    float4 w[8];
#pragma unroll
    for (int kk = 0; kk < 8; ++kk) w[kk] = *(const float4*)&wrow[kk * 64 + ko * 4];
#pragma unroll
    for (int j = 0; j < 8; ++j) {
      const float* xb = smem + (bh * 8 + j) * 512;
#pragma unroll
      for (int kk = 0; kk < 8; ++kk)
        acc[j] += dot4(*(const float4*)&xb[kk * 64 + ko * 4], w[kk]);
    }
  }
  __syncthreads();
  {  // stage h
    const float4* hg = (const float4*)hprev;
    float4* s4 = (float4*)smem;
    for (int i = tid; i < 4096; i += 256) s4[i] = hg[i];
  }
  __syncthreads();
  {  // phase 2: h @ Whh[row]^T
    const float* wrow = Whh + ((size_t)rr * H + hi) * H;
    float4 w[8];
#pragma unroll
    for (int kk = 0; kk < 8; ++kk) w[kk] = *(const float4*)&wrow[kk * 64 + ko * 4];
#pragma unroll
    for (int j = 0; j < 8; ++j) {
      const float* xb = smem + (bh * 8 + j) * 512;
#pragma unroll
      for (int kk = 0; kk < 8; ++kk)
        acc[j] += dot4(*(const float4*)&xb[kk * 64 + ko * 4], w[kk]);
    }
  }
  __syncthreads();   // all LDS reads done before gbuf overwrite

#pragma unroll
  for (int j = 0; j < 8; ++j) {
    acc[j] += __shfl_xor(acc[j], 1);
    acc[j] += __shfl_xor(acc[j], 2);
    acc[j] += __shfl_xor(acc[j], 4);
    acc[j] += __shfl_xor(acc[j], 8);
  }
  float* gbuf = smem;   // reuse (128 floats)
  if (ko == 0) {
    float bias = bih[rr * H + hi] + bhh[rr * H + hi];
#pragma unroll
    for (int j = 0; j < 8; ++j) gbuf[rr * 32 + bh * 8 + j] = acc[j] + bias;
  }
  __syncthreads();
  if (tid < 32) {
    int b = tid;
    float gi = gbuf[b], gf = gbuf[32 + b], gg = gbuf[64 + b], go = gbuf[96 + b];
    float c2 = sigf(gf) * cprev[b * H + hi] + sigf(gi) * tanhf(gg);
    hout[b * H + hi] = sigf(go) * tanhf(c2);
    cout[b * H + hi] = c2;
  }
}

// ---------------- fused vocab projection + q GEMV ----------------
// blocks 0..624: proj (16 v-rows, all 32 b). blocks 625..688: q (16 j, 32 lb).
// Weight rows fetched exactly once per dispatch.
__global__ __launch_bounds__(256) void projq_kernel(
    const float* __restrict__ xin,            // hmid top (or emb at t=0)
    const float* __restrict__ projW, const float* __restrict__ projb,
    float* __restrict__ logits, float* __restrict__ ocol, int direct, int tcol,
    const float* __restrict__ hmid_all, const float* __restrict__ Wq,
    const float* __restrict__ bq, float* __restrict__ q) {
  __shared__ __align__(16) float xs[32 * 512];   // 64 KB
  int blk = blockIdx.x, tid = threadIdx.x;
  int ko = tid & 15, vl = tid >> 4;

  if (blk < 625) {
    {
      const float4* xg = (const float4*)xin;
      float4* s4 = (float4*)xs;
      for (int i = tid; i < 4096; i += 256) s4[i] = xg[i];
    }
    __syncthreads();
    int v = blk * 16 + vl;
    const float* wrow = projW + (size_t)v * H;
    float4 w[8];
#pragma unroll
    for (int kk = 0; kk < 8; ++kk) w[kk] = *(const float4*)&wrow[kk * 64 + ko * 4];
    float acc[32];
#pragma unroll
    for (int b = 0; b < 32; ++b) acc[b] = 0.f;
    for (int b = 0; b < 32; ++b) {
      const float* xb = xs + b * 512;
#pragma unroll
      for (int kk = 0; kk < 8; ++kk)
        acc[b] += dot4(*(const float4*)&xb[kk * 64 + ko * 4], w[kk]);
    }
#pragma unroll
    for (int b = 0; b < 32; ++b) {
      acc[b] += __shfl_xor(acc[b], 1);
      acc[b] += __shfl_xor(acc[b], 2);
      acc[b] += __shfl_xor(acc[b], 4);
      acc[b] += __shfl_xor(acc[b], 8);
    }
    if (ko == 0) {
      float bias = projb[v];
      for (int b = 0; b < 32; ++b) {
        float r = acc[b] + bias;
        logits[b * V + v] = r;
        if (direct) ocol[((size_t)b * V + v) * T + tcol] = r;
        else        ocol[b * V + v] = r;
      }
    }
  } else {
    int b2 = blk - 625;
    int lg = b2 & 1, jg = b2 >> 1;
    {
      const float4* xg = (const float4*)(hmid_all + lg * 32 * H);
      float4* s4 = (float4*)xs;
      for (int i = tid; i < 4096; i += 256) s4[i] = xg[i];
    }
    __syncthreads();
    int j = jg * 16 + vl;
    const float* wrow = Wq + (size_t)j * H;
    float4 w[8];
#pragma unroll
    for (int kk = 0; kk < 8; ++kk) w[kk] = *(const float4*)&wrow[kk * 64 + ko * 4];
    float acc[32];
#pragma unroll
    for (int b = 0; b < 32; ++b) acc[b] = 0.f;
    for (int b = 0; b < 32; ++b) {
      const float* xb = xs + b * 512;
#pragma unroll
      for (int kk = 0; kk < 8; ++kk)
        acc[b] += dot4(*(const float4*)&xb[kk * 64 + ko * 4], w[kk]);
    }
#pragma unroll
    for (int b = 0; b < 32; ++b) {
      acc[b] += __shfl_xor(acc[b], 1);
      acc[b] += __shfl_xor(acc[b], 2);
      acc[b] += __shfl_xor(acc[b], 4);
      acc[b] += __shfl_xor(acc[b], 8);
    }
    if (ko == 0) {
      float bias = bq[j];
      for (int b = 0; b < 32; ++b)
        q[(lg * 32 + b) * H + j] = tanhf(acc[b] + bias);
    }
  }
}

// ---------------- scores -> softmax -> attn -> cat (per lb) ----------------
__global__ __launch_bounds__(256) void sattn_kernel(
    const float* __restrict__ q, const float* __restrict__ keysT,
    const float* __restrict__ valuesT, const float* __restrict__ hmid,
    float* __restrict__ cat) {
  __shared__ __align__(16) float qv[528];   // 4 chunks of 132 (128+4 skew)
  __shared__ float scl[64];
  __shared__ float wts[64];
  int lb = blockIdx.x, tid = threadIdx.x;
  int b = lb & 31;
  {
    int c0 = tid, c1 = tid + 256;
    qv[(c0 >> 7) * 132 + (c0 & 127)] = q[lb * H + c0];
    qv[(c1 >> 7) * 132 + (c1 & 127)] = q[lb * H + c1];
  }
  __syncthreads();
  int kq = tid & 3, sl = tid >> 2;
  float acc = 0.f;
  if (sl < S) {
    const float* kr = keysT + ((size_t)b * S + sl) * H + kq * 128;
    const float* qr = &qv[kq * 132];
    for (int k = 0; k < 128; k += 4)
      acc += dot4(*(const float4*)&qr[k], *(const float4*)&kr[k]);
  }
  acc += __shfl_xor(acc, 1);
  acc += __shfl_xor(acc, 2);
  if (kq == 0 && sl < S) scl[sl] = acc * (1.0f / 7.0f);
  __syncthreads();
  if (tid < 64) {
    float sc = (tid < S) ? scl[tid] : -3.4e38f;
    float m = sc;
    for (int o = 32; o > 0; o >>= 1) m = fmaxf(m, __shfl_xor(m, o));
    float e = (tid < S) ? expf(sc - m) : 0.f;
    float sum = e;
    for (int o = 32; o > 0; o >>= 1) sum += __shfl_xor(sum, o);
    if (tid < S) wts[tid] = e / sum;
  }
  __syncthreads();
  float acc0 = 0.f, acc1 = 0.f;
  for (int s = 0; s < S; ++s) {
    float w = wts[s];
    const float* vr = valuesT + ((size_t)b * S + s) * H;
    acc0 += w * vr[tid];
    acc1 += w * vr[tid + 256];
  }
  cat[lb * 1024 + tid] = acc0;
  cat[lb * 1024 + tid + 256] = acc1;
  cat[lb * 1024 + 512 + tid] = hmid[lb * H + tid];
  cat[lb * 1024 + 768 + tid] = hmid[lb * H + tid + 256];
}

// ---------------- fused gated-hidden-update + argmax/embed ----------------
// blocks 0..127: hatt (16 j x 16 lb). blocks 128..159: argmax for b=blk-128.
__global__ __launch_bounds__(256) void hattarg_kernel(
    const float* __restrict__ cat, const float* __restrict__ hattW,
    const float* __restrict__ hattb, float* __restrict__ h,
    const float* __restrict__ logits, const float* __restrict__ embed,
    float* __restrict__ emb) {
  __shared__ __align__(16) float smem[16 * 1024];   // 64 KB
  int blk = blockIdx.x, tid = threadIdx.x;
  if (blk < 128) {
    int lbg = blk & 3, jg = blk >> 2;
    {
      const float4* cg = (const float4*)(cat + lbg * 16 * 1024);
      float4* s4 = (float4*)smem;
      for (int i = tid; i < 4096; i += 256) s4[i] = cg[i];
    }
    __syncthreads();
    int ko = tid & 15, jl = tid >> 4;
    int j = jg * 16 + jl;
    const float* wrow = hattW + (size_t)j * 1024;
    float4 w[16];
#pragma unroll
    for (int kk = 0; kk < 16; ++kk) w[kk] = *(const float4*)&wrow[kk * 64 + ko * 4];
    float acc[16];
#pragma unroll
    for (int lb = 0; lb < 16; ++lb) acc[lb] = 0.f;
    for (int lb = 0; lb < 16; ++lb) {
      const float* cb = smem + lb * 1024;
#pragma unroll
      for (int kk = 0; kk < 16; ++kk)
        acc[lb] += dot4(*(const float4*)&cb[kk * 64 + ko * 4], w[kk]);
    }
#pragma unroll
    for (int lb = 0; lb < 16; ++lb) {
      acc[lb] += __shfl_xor(acc[lb], 1);
      acc[lb] += __shfl_xor(acc[lb], 2);
      acc[lb] += __shfl_xor(acc[lb], 4);
      acc[lb] += __shfl_xor(acc[lb], 8);
    }
    if (ko == 0) {
      float bias = hattb[j];
      for (int lb = 0; lb < 16; ++lb)
        h[(lbg * 16 + lb) * H + j] = tanhf(acc[lb] + bias);
    }
  } else {
    int b = blk - 128;
    float* sv = smem;
    int* si = (int*)(smem + 256);
    float best = -3.4e38f;
    int bi = 0x7fffffff;
    for (int it = 0; it < 10; ++it) {
      int v0 = it * 1024 + tid * 4;
      if (v0 < V) {
        float4 lv = *(const float4*)&logits[b * V + v0];
        if (lv.x > best) { best = lv.x; bi = v0; }
        if (lv.y > best) { best = lv.y; bi = v0 + 1; }
        if (lv.z > best) { best = lv.z; bi = v0 + 2; }
        if (lv.w > best) { best = lv.w; bi = v0 + 3; }
      }
    }
    sv[tid] = best; si[tid] = bi;
    __syncthreads();
    for (int st = 128; st > 0; st >>= 1) {
      if (tid < st) {
        float ov = sv[tid + st]; int oi = si[tid + st];
        if (ov > sv[tid] || (ov == sv[tid] && oi < si[tid])) { sv[tid] = ov; si[tid] = oi; }
      }
      __syncthreads();
    }
    int idx = si[0];
    for (int i = tid; i < H; i += 256) emb[b * H + i] = embed[(size_t)idx * H + i];
  }
}

// ---------------- final transpose (staged): slog[t][b][v] -> out[b][v][t] --
__global__ __launch_bounds__(256) void finalize_kernel(
    const float* __restrict__ slog, float* __restrict__ outp) {
  int idx = blockIdx.x * 256 + threadIdx.x;   // b*V + v, exact 320000
  float vals[T];
#pragma unroll
  for (int t = 0; t < T; ++t) vals[t] = slog[(size_t)t * (B * V) + idx];
#pragma unroll
  for (int t = 0; t < T; t += 4)
    *(float4*)&outp[(size_t)idx * T + t] =
        make_float4(vals[t], vals[t + 1], vals[t + 2], vals[t + 3]);
}

}  // namespace

extern "C" void kernel_launch(void* const* d_in, const int* in_sizes, int n_in,
                              void* d_out, int out_size, void* d_ws, size_t ws_size,
                              hipStream_t stream) {
  const float* chan   = (const float*)d_in[0];
  const float* pooled = (const float*)d_in[1];
  const float* embed  = (const float*)d_in[2];
  const float* Wq     = (const float*)d_in[3];
  const float* bq     = (const float*)d_in[4];
  const float* Wk     = (const float*)d_in[5];
  const float* bk     = (const float*)d_in[6];
  const float* Wv     = (const float*)d_in[7];
  const float* bv     = (const float*)d_in[8];
  const float* Wih    = (const float*)d_in[9];
  const float* Whh    = (const float*)d_in[10];
  const float* bih    = (const float*)d_in[11];
  const float* bhh    = (const float*)d_in[12];
  const float* projW  = (const float*)d_in[13];
  const float* projb  = (const float*)d_in[14];
  const float* hattW  = (const float*)d_in[15];
  const float* hattb  = (const float*)d_in[16];
  const int*   sos    = (const int*)d_in[17];

  float* out = (float*)d_out;
  float* ws  = (float*)d_ws;

  float* keysT   = ws;                        // B*S*512
  float* valuesT = keysT + B * S * 512;       // B*S*512
  float* emb     = valuesT + B * S * 512;     // B*H
  float* h       = emb + B * H;               // L*B*H
  float* c       = h + L * B * H;             // L*B*H
  float* hmid    = c + L * B * H;             // L*B*H
  float* cat     = hmid + L * B * H;          // L*B*1024
  float* q       = cat + L * B * 1024;        // L*B*H
  float* logits  = q + L * B * H;             // B*V
  float* slog    = logits + B * V;            // T*B*V (staged mode)

  size_t base_floats = (size_t)(slog - ws);
  bool staged = ws_size >= (base_floats + (size_t)T * B * V) * sizeof(float);

  kv_kernel<<<256, 256, 0, stream>>>(chan, Wk, bk, Wv, bv, keysT, valuesT);
  init_kernel<<<(L * B * H) / 256, 256, 0, stream>>>(pooled, embed, sos, emb, h, c);
  {
    float* oc = staged ? slog : out;
    projq_kernel<<<625, 256, 0, stream>>>(emb, projW, projb, logits, oc,
                                          staged ? 0 : 1, 0,
                                          hmid, Wq, bq, q);
  }

  for (int t = 0; t < T - 1; ++t) {
    float* oc = staged ? (slog + (size_t)(t + 1) * B * V) : out;
    lstm_kernel<<<512, 256, 0, stream>>>(emb, h, c, Wih, Whh, bih, bhh, hmid, c);
    lstm_kernel<<<512, 256, 0, stream>>>(hmid, h + B * H, c + B * H,
                                         Wih + 4 * H * H, Whh + 4 * H * H,
                                         bih + 4 * H, bhh + 4 * H,
                                         hmid + B * H, c + B * H);
    projq_kernel<<<689, 256, 0, stream>>>(hmid + B * H, projW, projb, logits, oc,
                                          staged ? 0 : 1, t + 1,
                                          hmid, Wq, bq, q);
    sattn_kernel<<<L * B, 256, 0, stream>>>(q, keysT, valuesT, hmid, cat);
    hattarg_kernel<<<160, 256, 0, stream>>>(cat, hattW, hattb, h,
                                            logits, embed, emb);
  }

  if (staged) finalize_kernel<<<(B * V) / 256, 256, 0, stream>>>(slog, out);
}